// Round 1
// baseline (140.529 us; speedup 1.0000x reference)
//
#include <hip/hip_runtime.h>
#include <hip/hip_bf16.h>

// NodeTypeConcatSheafLearner: out[e] = tanh(concat(x[src],x[dst],oh[src],oh[dst]) @ W^T)
// Factorized: per-node projections Psrc/Pdst (N x 9), per-edge add+tanh.

#define ODIM 9      // 3*3 output maps per edge
#define INF 72      // 2*32 + 2*4 input features of W rows
#define PSTRIDE 12  // pad 9 -> 12 floats so rows are 48B, float4-aligned
#define TPB 256

__device__ __forceinline__ float fast_tanh(float v) {
    // tanh(v) = 1 - 2/(exp(2v)+1); exp->inf and exp->0 limits give +/-1 exactly.
    float e = __expf(2.0f * v);
    return 1.0f - 2.0f * __builtin_amdgcn_rcpf(e + 1.0f);
}

__global__ __launch_bounds__(TPB) void node_proj_kernel(
        const float* __restrict__ x, const int* __restrict__ nt,
        const float* __restrict__ W, float* __restrict__ Psrc,
        float* __restrict__ Pdst, int N) {
    int n = blockIdx.x * TPB + threadIdx.x;
    if (n >= N) return;
    float xv[32];
    const float4* xp = (const float4*)(x + (size_t)n * 32);
    #pragma unroll
    for (int i = 0; i < 8; ++i) {
        float4 r = xp[i];
        xv[4*i+0] = r.x; xv[4*i+1] = r.y; xv[4*i+2] = r.z; xv[4*i+3] = r.w;
    }
    int t = nt[n];
    float* ps = Psrc + (size_t)n * PSTRIDE;
    float* pd = Pdst + (size_t)n * PSTRIDE;
    #pragma unroll
    for (int o = 0; o < ODIM; ++o) {
        const float* wr = W + o * INF;  // uniform address -> scalar loads
        float s1 = wr[64 + t];          // one-hot(src type) contribution
        float s2 = wr[68 + t];          // one-hot(dst type) contribution
        #pragma unroll
        for (int f = 0; f < 32; ++f) {
            s1 += xv[f] * wr[f];
            s2 += xv[f] * wr[32 + f];
        }
        ps[o] = s1;
        pd[o] = s2;
    }
}

__global__ __launch_bounds__(TPB) void edge_kernel(
        const int* __restrict__ src, const int* __restrict__ dst,
        const float* __restrict__ Psrc, const float* __restrict__ Pdst,
        float* __restrict__ out, int E) {
    __shared__ __align__(16) float tile[TPB * ODIM];
    int e0 = blockIdx.x * TPB;
    int cnt = min(TPB, E - e0);
    int e = e0 + (int)threadIdx.x;
    if ((int)threadIdx.x < cnt) {
        int s = src[e];
        int d = dst[e];
        const float4* ps = (const float4*)(Psrc + (size_t)s * PSTRIDE);
        const float4* pd = (const float4*)(Pdst + (size_t)d * PSTRIDE);
        float4 a0 = ps[0], a1 = ps[1], a2 = ps[2];
        float4 b0 = pd[0], b1 = pd[1], b2 = pd[2];
        float v[ODIM] = {a0.x+b0.x, a0.y+b0.y, a0.z+b0.z, a0.w+b0.w,
                         a1.x+b1.x, a1.y+b1.y, a1.z+b1.z, a1.w+b1.w,
                         a2.x+b2.x};
        #pragma unroll
        for (int k = 0; k < ODIM; ++k)
            tile[threadIdx.x * ODIM + k] = fast_tanh(v[k]);
    }
    __syncthreads();
    if (cnt == TPB) {
        // 2304 floats = 576 float4, contiguous, 16B-aligned (e0*36 % 16 == 0)
        float4* o4 = (float4*)(out + (size_t)e0 * ODIM);
        const float4* t4 = (const float4*)tile;
        for (int i = threadIdx.x; i < TPB * ODIM / 4; i += TPB)
            o4[i] = t4[i];
    } else {
        for (int i = threadIdx.x; i < cnt * ODIM; i += TPB)
            out[(size_t)e0 * ODIM + i] = tile[i];
    }
}

// Fallback if workspace is too small for the P tables: fully fused per-edge.
__global__ __launch_bounds__(TPB) void edge_fused_kernel(
        const int* __restrict__ src, const int* __restrict__ dst,
        const float* __restrict__ x, const int* __restrict__ nt,
        const float* __restrict__ W, float* __restrict__ out, int E) {
    __shared__ __align__(16) float tile[TPB * ODIM];
    int e0 = blockIdx.x * TPB;
    int cnt = min(TPB, E - e0);
    int e = e0 + (int)threadIdx.x;
    if ((int)threadIdx.x < cnt) {
        int s = src[e];
        int d = dst[e];
        float xs[32], xd[32];
        const float4* xsp = (const float4*)(x + (size_t)s * 32);
        const float4* xdp = (const float4*)(x + (size_t)d * 32);
        #pragma unroll
        for (int i = 0; i < 8; ++i) {
            float4 rs = xsp[i], rd = xdp[i];
            xs[4*i+0]=rs.x; xs[4*i+1]=rs.y; xs[4*i+2]=rs.z; xs[4*i+3]=rs.w;
            xd[4*i+0]=rd.x; xd[4*i+1]=rd.y; xd[4*i+2]=rd.z; xd[4*i+3]=rd.w;
        }
        int ts = nt[s], td = nt[d];
        #pragma unroll
        for (int o = 0; o < ODIM; ++o) {
            const float* wr = W + o * INF;
            float acc = wr[64 + ts] + wr[68 + td];
            #pragma unroll
            for (int f = 0; f < 32; ++f)
                acc += xs[f] * wr[f] + xd[f] * wr[32 + f];
            tile[threadIdx.x * ODIM + o] = fast_tanh(acc);
        }
    }
    __syncthreads();
    if (cnt == TPB) {
        float4* o4 = (float4*)(out + (size_t)e0 * ODIM);
        const float4* t4 = (const float4*)tile;
        for (int i = threadIdx.x; i < TPB * ODIM / 4; i += TPB)
            o4[i] = t4[i];
    } else {
        for (int i = threadIdx.x; i < cnt * ODIM; i += TPB)
            out[(size_t)e0 * ODIM + i] = tile[i];
    }
}

extern "C" void kernel_launch(void* const* d_in, const int* in_sizes, int n_in,
                              void* d_out, int out_size, void* d_ws, size_t ws_size,
                              hipStream_t stream) {
    const float* x  = (const float*)d_in[0];
    const int*   ei = (const int*)d_in[1];   // [2, E] (harness passes integers as int32)
    const int*   nt = (const int*)d_in[2];   // [N]
    const float* W  = (const float*)d_in[3]; // [9, 72]
    float* out = (float*)d_out;

    int N = in_sizes[2];
    int E = in_sizes[1] / 2;
    const int* src = ei;
    const int* dst = ei + E;

    size_t pbytes = (size_t)N * PSTRIDE * sizeof(float);
    if (ws_size >= 2 * pbytes) {
        float* Psrc = (float*)d_ws;
        float* Pdst = (float*)((char*)d_ws + pbytes);
        node_proj_kernel<<<(N + TPB - 1) / TPB, TPB, 0, stream>>>(x, nt, W, Psrc, Pdst, N);
        edge_kernel<<<(E + TPB - 1) / TPB, TPB, 0, stream>>>(src, dst, Psrc, Pdst, out, E);
    } else {
        edge_fused_kernel<<<(E + TPB - 1) / TPB, TPB, 0, stream>>>(src, dst, x, nt, W, out, E);
    }
}

// Round 2
// 125.135 us; speedup vs baseline: 1.1230x; 1.1230x over previous
//
#include <hip/hip_runtime.h>
#include <hip/hip_bf16.h>
#include <hip/hip_fp16.h>

// NodeTypeConcatSheafLearner: out[e] = tanh(concat(x[src],x[dst],oh[src],oh[dst]) @ W^T)
// Factorized: per-node projections P (N x 2 x 9, fp16, one 64B line per node),
// then per-edge gather + add + tanh.
//
// P row layout (64 B, cache-line aligned):
//   bytes [ 0,18): Psrc[n][0..9) as fp16   (pad to 32)
//   bytes [32,50): Pdst[n][0..9) as fp16   (pad to 64)
// One gather = exactly one 64-B line; a line fetched for Psrc[n] also
// caches Pdst[n] (src/dst share the node distribution -> cross-hits).

#define ODIM 9      // 3*3 output maps per edge
#define INF 72      // 2*32 + 2*4 input features of W rows
#define ROWB 64     // bytes per node row in P
#define TPB 256

__device__ __forceinline__ float fast_tanh(float v) {
    // tanh(v) = 1 - 2/(exp(2v)+1); exp->inf and exp->0 limits give +/-1 exactly.
    float e = __expf(2.0f * v);
    return 1.0f - 2.0f * __builtin_amdgcn_rcpf(e + 1.0f);
}

__global__ __launch_bounds__(TPB) void node_proj_kernel(
        const float* __restrict__ x, const int* __restrict__ nt,
        const float* __restrict__ W, char* __restrict__ P, int N) {
    int n = blockIdx.x * TPB + threadIdx.x;
    if (n >= N) return;
    float xv[32];
    const float4* xp = (const float4*)(x + (size_t)n * 32);
    #pragma unroll
    for (int i = 0; i < 8; ++i) {
        float4 r = xp[i];
        xv[4*i+0] = r.x; xv[4*i+1] = r.y; xv[4*i+2] = r.z; xv[4*i+3] = r.w;
    }
    int t = nt[n];
    unsigned short hs[10], hd[10];
    #pragma unroll
    for (int o = 0; o < ODIM; ++o) {
        const float* wr = W + o * INF;  // wave-uniform base -> scalar loads
        float s1 = wr[64 + t];          // one-hot(src type) contribution
        float s2 = wr[68 + t];          // one-hot(dst type) contribution
        #pragma unroll
        for (int f = 0; f < 32; ++f) {
            s1 += xv[f] * wr[f];
            s2 += xv[f] * wr[32 + f];
        }
        __half h1 = __float2half(s1), h2 = __float2half(s2);
        hs[o] = *(unsigned short*)&h1;
        hd[o] = *(unsigned short*)&h2;
    }
    hs[9] = 0; hd[9] = 0;
    char* row = P + (size_t)n * ROWB;
    union { unsigned short u[8]; uint4 v; } pk;
    #pragma unroll
    for (int i = 0; i < 8; ++i) pk.u[i] = hs[i];
    *(uint4*)(row + 0) = pk.v;
    *(unsigned int*)(row + 16) = (unsigned int)hs[8] | ((unsigned int)hs[9] << 16);
    #pragma unroll
    for (int i = 0; i < 8; ++i) pk.u[i] = hd[i];
    *(uint4*)(row + 32) = pk.v;
    *(unsigned int*)(row + 48) = (unsigned int)hd[8] | ((unsigned int)hd[9] << 16);
}

__device__ __forceinline__ void load9h(const char* p, float* v) {
    uint4 u = *(const uint4*)p;                 // halves 0..7
    unsigned int u2 = *(const unsigned int*)(p + 16);  // half 8 (+zero pad)
    const __half2* h = (const __half2*)&u;
    #pragma unroll
    for (int i = 0; i < 4; ++i) {
        float2 f = __half22float2(h[i]);
        v[2*i] = f.x; v[2*i+1] = f.y;
    }
    __half h8 = *(const __half*)&u2;
    v[8] = __half2float(h8);
}

__global__ __launch_bounds__(TPB) void edge_kernel(
        const int* __restrict__ src, const int* __restrict__ dst,
        const char* __restrict__ P, float* __restrict__ out, int E) {
    __shared__ __align__(16) float tile[TPB * ODIM];
    int e0 = blockIdx.x * TPB;
    int cnt = min(TPB, E - e0);
    int e = e0 + (int)threadIdx.x;
    if ((int)threadIdx.x < cnt) {
        int s = src[e];
        int d = dst[e];
        float vs[ODIM], vd[ODIM];
        load9h(P + (size_t)s * ROWB, vs);
        load9h(P + (size_t)d * ROWB + 32, vd);
        #pragma unroll
        for (int k = 0; k < ODIM; ++k)
            tile[threadIdx.x * ODIM + k] = fast_tanh(vs[k] + vd[k]);
    }
    __syncthreads();
    if (cnt == TPB) {
        // 2304 floats = 576 float4, contiguous, 16B-aligned (e0*36 % 16 == 0)
        float4* o4 = (float4*)(out + (size_t)e0 * ODIM);
        const float4* t4 = (const float4*)tile;
        for (int i = threadIdx.x; i < TPB * ODIM / 4; i += TPB)
            o4[i] = t4[i];
    } else {
        for (int i = threadIdx.x; i < cnt * ODIM; i += TPB)
            out[(size_t)e0 * ODIM + i] = tile[i];
    }
}

// Fallback if workspace is too small for the P table: fully fused per-edge.
__global__ __launch_bounds__(TPB) void edge_fused_kernel(
        const int* __restrict__ src, const int* __restrict__ dst,
        const float* __restrict__ x, const int* __restrict__ nt,
        const float* __restrict__ W, float* __restrict__ out, int E) {
    __shared__ __align__(16) float tile[TPB * ODIM];
    int e0 = blockIdx.x * TPB;
    int cnt = min(TPB, E - e0);
    int e = e0 + (int)threadIdx.x;
    if ((int)threadIdx.x < cnt) {
        int s = src[e];
        int d = dst[e];
        float xs[32], xd[32];
        const float4* xsp = (const float4*)(x + (size_t)s * 32);
        const float4* xdp = (const float4*)(x + (size_t)d * 32);
        #pragma unroll
        for (int i = 0; i < 8; ++i) {
            float4 rs = xsp[i], rd = xdp[i];
            xs[4*i+0]=rs.x; xs[4*i+1]=rs.y; xs[4*i+2]=rs.z; xs[4*i+3]=rs.w;
            xd[4*i+0]=rd.x; xd[4*i+1]=rd.y; xd[4*i+2]=rd.z; xd[4*i+3]=rd.w;
        }
        int ts = nt[s], td = nt[d];
        #pragma unroll
        for (int o = 0; o < ODIM; ++o) {
            const float* wr = W + o * INF;
            float acc = wr[64 + ts] + wr[68 + td];
            #pragma unroll
            for (int f = 0; f < 32; ++f)
                acc += xs[f] * wr[f] + xd[f] * wr[32 + f];
            tile[threadIdx.x * ODIM + o] = fast_tanh(acc);
        }
    }
    __syncthreads();
    if (cnt == TPB) {
        float4* o4 = (float4*)(out + (size_t)e0 * ODIM);
        const float4* t4 = (const float4*)tile;
        for (int i = threadIdx.x; i < TPB * ODIM / 4; i += TPB)
            o4[i] = t4[i];
    } else {
        for (int i = threadIdx.x; i < cnt * ODIM; i += TPB)
            out[(size_t)e0 * ODIM + i] = tile[i];
    }
}

extern "C" void kernel_launch(void* const* d_in, const int* in_sizes, int n_in,
                              void* d_out, int out_size, void* d_ws, size_t ws_size,
                              hipStream_t stream) {
    const float* x  = (const float*)d_in[0];
    const int*   ei = (const int*)d_in[1];   // [2, E]
    const int*   nt = (const int*)d_in[2];   // [N]
    const float* W  = (const float*)d_in[3]; // [9, 72]
    float* out = (float*)d_out;

    int N = in_sizes[2];
    int E = in_sizes[1] / 2;
    const int* src = ei;
    const int* dst = ei + E;

    size_t pbytes = (size_t)N * ROWB;
    if (ws_size >= pbytes) {
        char* P = (char*)d_ws;
        node_proj_kernel<<<(N + TPB - 1) / TPB, TPB, 0, stream>>>(x, nt, W, P, N);
        edge_kernel<<<(E + TPB - 1) / TPB, TPB, 0, stream>>>(src, dst, P, out, E);
    } else {
        edge_fused_kernel<<<(E + TPB - 1) / TPB, TPB, 0, stream>>>(src, dst, x, nt, W, out, E);
    }
}